// Round 1
// baseline (302.661 us; speedup 1.0000x reference)
//
#include <hip/hip_runtime.h>
#include <math.h>

#define B_ 8
#define T_ 256
#define IDIM_ 128
#define ODIM_ 128
#define HDIM_ 512
#define CDIM_ 128
#define NROWS_ (B_*T_)
#define NSHIFT_ 255
#define TEMPER_ 5.0f
#define ENERGY_TH_ 100.0f
#define N_ITER_ 4

struct WsHeader {
  double loss[N_ITER_];
  unsigned int cnt_y_nz;
  unsigned int cnt_rows_nm;
};

__global__ void k_zero(WsHeader* h) {
  for (int i = 0; i < N_ITER_; ++i) h->loss[i] = 0.0;
  h->cnt_y_nz = 0u;
  h->cnt_rows_nm = 0u;
}

__global__ __launch_bounds__(128) void k_count(const float* __restrict__ y, WsHeader* h) {
  __shared__ int red[128];
  const int row = blockIdx.x, tid = threadIdx.x;
  float v = y[row * ODIM_ + tid];
  red[tid] = (v != 0.0f) ? 1 : 0;
  __syncthreads();
  for (int off = 64; off > 0; off >>= 1) {
    if (tid < off) red[tid] += red[tid + off];
    __syncthreads();
  }
  if (tid == 0) {
    unsigned c = (unsigned)red[0];
    atomicAdd(&h->cnt_y_nz, c);
    if (c > 0) atomicAdd(&h->cnt_rows_nm, 1u);
  }
}

__device__ inline float block_sum(float v, float* s_red) {
  const int tid = threadIdx.x;
  s_red[tid] = v; __syncthreads();
  for (int off = 128; off > 0; off >>= 1) {
    if (tid < off) s_red[tid] += s_red[tid + off];
    __syncthreads();
  }
  float r = s_red[0]; __syncthreads();
  return r;
}

__device__ inline float block_max(float v, float* s_red) {
  const int tid = threadIdx.x;
  s_red[tid] = v; __syncthreads();
  for (int off = 128; off > 0; off >>= 1) {
    if (tid < off) s_red[tid] = fmaxf(s_red[tid], s_red[tid + off]);
    __syncthreads();
  }
  float r = s_red[0]; __syncthreads();
  return r;
}

// top-128-of-512 mask with exact lax.top_k tie semantics (lower index wins).
// energy = h*h >= 0, so uint bit-order == float order. Composite key packs
// (511-idx) into low 32 bits so equal energies prefer smaller index.
__device__ inline void topk128_from_energy(const float* __restrict__ hsrc,
                                           float* __restrict__ mask,
                                           unsigned long long* __restrict__ keys) {
  const int tid = threadIdx.x;
  for (int c = tid; c < HDIM_; c += 256) {
    float e = hsrc[c] * hsrc[c];
    keys[c] = (((unsigned long long)__float_as_uint(e)) << 32) |
              (unsigned long long)(HDIM_ - 1 - c);
    mask[c] = 0.f;
  }
  __syncthreads();
  // bitonic sort, 512 elems, descending, 256 threads
  for (int k = 2; k <= HDIM_; k <<= 1) {
    for (int j = k >> 1; j > 0; j >>= 1) {
      int i = ((tid & ~(j - 1)) << 1) | (tid & (j - 1));
      int p = i | j;
      unsigned long long a = keys[i], b = keys[p];
      bool desc = ((i & k) == 0);
      if (desc ? (a < b) : (a > b)) { keys[i] = b; keys[p] = a; }
      __syncthreads();
    }
  }
  if (tid < CDIM_) {
    int idx = (HDIM_ - 1) - (int)(keys[tid] & 0xffffffffull);
    mask[idx] = 1.f;
  }
  __syncthreads();
}

__global__ __launch_bounds__(256) void k_main(
    const float* __restrict__ gx, const float* __restrict__ gy,
    const float* __restrict__ enc_w, const float* __restrict__ enc_b,
    const float* __restrict__ dec_w, const float* __restrict__ dec_b,
    WsHeader* __restrict__ hdr)
{
  const int row = blockIdx.x;
  const int tid = threadIdx.x;

  __shared__ float s_x[IDIM_];
  __shared__ float s_y[ODIM_];
  __shared__ float s_yal[ODIM_];
  __shared__ float s_yatt[ODIM_];
  __shared__ float s_yele[ODIM_];
  __shared__ float s_h[HDIM_];
  __shared__ float s_mprev[HDIM_];
  __shared__ float s_mcur[HDIM_];
  __shared__ float s_mcur0[HDIM_];
  __shared__ unsigned long long s_keys[HDIM_];
  __shared__ float s_sim[256];
  __shared__ float s_red[256];
  __shared__ int   s_redi[256];
  __shared__ unsigned char s_seqm[ODIM_];

  if (tid < IDIM_) s_x[tid] = gx[row * IDIM_ + tid];
  if (tid < ODIM_) {
    float v = gy[row * ODIM_ + tid];
    s_y[tid] = v;
    s_seqm[tid] = (v == 0.0f) ? 1 : 0;
  }
  s_mprev[tid] = 0.f;
  s_mprev[tid + 256] = 0.f;
  __syncthreads();

  const float denom_ll = (float)max(hdr->cnt_y_nz, 1u);
  const float denomh   = (float)max(hdr->cnt_rows_nm * (unsigned)HDIM_, 1u);

  // sm_row = all(y_row == 0)
  float nzv = (tid < ODIM_ && !s_seqm[tid]) ? 1.f : 0.f;
  const bool sm_row = (block_sum(nzv, s_red) == 0.f);

  for (int iter = 0; iter < N_ITER_; ++iter) {
    // ---- ||y_res||
    float yy = (tid < ODIM_) ? s_y[tid] * s_y[tid] : 0.f;
    const float normy = sqrtf(block_sum(yy, s_red));

    // ---- sim over 255 shifts (cross-correlation of x_res with y_res)
    if (tid < NSHIFT_) {
      int jlo = 127 - tid; if (jlo < 0) jlo = 0;
      int jhi = 254 - tid; if (jhi > 127) jhi = 127;
      float dot = 0.f, nx = 0.f;
      int base = tid - 127;
      for (int j = jlo; j <= jhi; ++j) {
        float xv = s_x[base + j];
        dot += xv * s_y[j];
        nx  += xv * xv;
      }
      float den = normy * sqrtf(nx);
      s_sim[tid] = (den == 0.f) ? 0.f : dot / den;
    } else {
      s_sim[tid] = -INFINITY;
    }
    __syncthreads();

    // ---- argmax (first occurrence of max)
    s_red[tid] = s_sim[tid]; s_redi[tid] = tid;
    __syncthreads();
    for (int off = 128; off > 0; off >>= 1) {
      if (tid < off) {
        float v2 = s_red[tid + off]; int i2 = s_redi[tid + off];
        if (v2 > s_red[tid] || (v2 == s_red[tid] && i2 < s_redi[tid])) {
          s_red[tid] = v2; s_redi[tid] = i2;
        }
      }
      __syncthreads();
    }
    const int theta = s_redi[0];
    __syncthreads();

    // ---- y_al = selected shifted window of x_res
    if (tid < ODIM_) {
      int i = theta - 127 + tid;
      s_yal[tid] = (i >= 0 && i < IDIM_) ? s_x[i] : 0.f;
    }
    __syncthreads();

    // ---- softmax(y_al * y_res / TEMPER) -> y_att
    float z = (tid < ODIM_) ? (s_yal[tid] * s_y[tid] / TEMPER_) : -INFINITY;
    const float zmax = block_max(z, s_red);
    float e = (tid < ODIM_) ? expf(z - zmax) : 0.f;
    const float esum = block_sum(e, s_red);
    if (tid < ODIM_) s_yatt[tid] = s_yal[tid] * (e / esum);
    __syncthreads();

    // ---- h = y_att @ enc_w + enc_b   (128 -> 512)
    for (int c = tid; c < HDIM_; c += 256) {
      float acc = 0.f;
      #pragma unroll 8
      for (int i = 0; i < IDIM_; ++i) acc += s_yatt[i] * enc_w[i * HDIM_ + c];
      s_h[c] = acc + enc_b[c];
    }
    __syncthreads();

    // ---- hsr
    float row_lh = 0.f;
    if (iter == 0) {
      topk128_from_energy(s_h, s_mcur, s_keys);
      for (int c = tid; c < HDIM_; c += 256) s_mprev[c] = s_mcur[c];
    } else {
      topk128_from_energy(s_h, s_mcur0, s_keys);
      float lacc = 0.f;
      for (int c = tid; c < HDIM_; c += 256) {
        float mi = s_mprev[c] * s_mcur0[c];
        if (mi > 0.f && !sm_row) {
          float d = s_h[c] - (1.0f - mi);
          lacc += (d * d) / denomh;
        }
      }
      row_lh = block_sum(lacc, s_red);
      // zero previously-selected channels
      for (int c = tid; c < HDIM_; c += 256)
        if (s_mprev[c] > 0.f) s_h[c] = 0.f;
      __syncthreads();
      topk128_from_energy(s_h, s_mcur, s_keys);
      for (int c = tid; c < HDIM_; c += 256) s_mprev[c] += s_mcur[c];
    }
    // keep only current top-k channels
    for (int c = tid; c < HDIM_; c += 256)
      s_h[c] = (s_mcur[c] > 0.f) ? s_h[c] : 0.f;
    __syncthreads();

    // ---- y_ele = h @ dec_w + dec_b   (512 -> 128)
    if (tid < ODIM_) {
      float acc = 0.f;
      #pragma unroll 8
      for (int c = 0; c < HDIM_; ++c) acc += s_h[c] * dec_w[c * ODIM_ + tid];
      s_yele[tid] = acc + dec_b[tid];
    }
    __syncthreads();

    // ---- energy_loss
    const float tshift  = fabsf((float)theta - 127.0f);
    const float menergy = tshift + 1.0f;
    const bool  mmask   = (tshift > ENERGY_TH_);
    float lacc2 = 0.f;
    if (tid < ODIM_) {
      float d = s_yele[tid] - s_y[tid];
      float l = s_seqm[tid] ? 0.f : d * d;
      l = l / denom_ll;
      l = mmask ? 0.f : l;
      l = l / menergy;
      lacc2 = l;
    }
    float row_ll = block_sum(lacc2, s_red);
    if (tid == 0) atomicAdd(&hdr->loss[iter], (double)(row_ll + row_lh));

    // ---- residual updates
    if (tid < ODIM_) {
      float ynew = s_y[tid] - s_yele[tid];
      int src = tid + 127 - theta;                 // x_ele[j] = y_att[j+127-theta]
      float xe = (src >= 0 && src < ODIM_) ? s_yatt[src] : 0.f;
      float xnew = s_x[tid] - xe;
      s_y[tid] = ynew;
      s_x[tid] = xnew;
    }
    __syncthreads();
  }
}

__global__ void k_finish(const WsHeader* __restrict__ h, float* __restrict__ out) {
  double s = (h->loss[0] + h->loss[1] + h->loss[2] + h->loss[3]) * 0.25;
  out[0] = (float)s;
}

extern "C" void kernel_launch(void* const* d_in, const int* in_sizes, int n_in,
                              void* d_out, int out_size, void* d_ws, size_t ws_size,
                              hipStream_t stream) {
  (void)in_sizes; (void)n_in; (void)out_size; (void)ws_size;
  const float* x     = (const float*)d_in[0];
  const float* y     = (const float*)d_in[1];
  const float* enc_w = (const float*)d_in[2];
  const float* enc_b = (const float*)d_in[3];
  const float* dec_w = (const float*)d_in[4];
  const float* dec_b = (const float*)d_in[5];
  float* out = (float*)d_out;
  WsHeader* hdr = (WsHeader*)d_ws;

  hipLaunchKernelGGL(k_zero,   dim3(1),      dim3(1),   0, stream, hdr);
  hipLaunchKernelGGL(k_count,  dim3(NROWS_), dim3(128), 0, stream, y, hdr);
  hipLaunchKernelGGL(k_main,   dim3(NROWS_), dim3(256), 0, stream,
                     x, y, enc_w, enc_b, dec_w, dec_b, hdr);
  hipLaunchKernelGGL(k_finish, dim3(1),      dim3(1),   0, stream, hdr, out);
}

// Round 2
// 223.402 us; speedup vs baseline: 1.3548x; 1.3548x over previous
//
#include <hip/hip_runtime.h>
#include <math.h>

#define B_ 8
#define T_ 256
#define IDIM_ 128
#define ODIM_ 128
#define HDIM_ 512
#define CDIM_ 128
#define NROWS_ (B_*T_)
#define TEMPER_ 5.0f
#define ENERGY_TH_ 100.0f
#define N_ITER_ 4
#define XPAD_ 384   // [0,127) zeros | [127,255) x | [255,384) zeros

struct WsHeader {
  double loss[N_ITER_];
  unsigned int cnt_y_nz;
  unsigned int cnt_rows_nm;
};

__global__ void k_zero(WsHeader* h) {
  for (int i = 0; i < N_ITER_; ++i) h->loss[i] = 0.0;
  h->cnt_y_nz = 0u;
  h->cnt_rows_nm = 0u;
}

__global__ __launch_bounds__(128) void k_count(const float* __restrict__ y, WsHeader* h) {
  __shared__ int red[128];
  const int row = blockIdx.x, tid = threadIdx.x;
  float v = y[row * ODIM_ + tid];
  red[tid] = (v != 0.0f) ? 1 : 0;
  __syncthreads();
  for (int off = 64; off > 0; off >>= 1) {
    if (tid < off) red[tid] += red[tid + off];
    __syncthreads();
  }
  if (tid == 0) {
    unsigned c = (unsigned)red[0];
    atomicAdd(&h->cnt_y_nz, c);
    if (c > 0) atomicAdd(&h->cnt_rows_nm, 1u);
  }
}

// ---- wave-level (64-lane) primitives; xor-butterfly replicates the LDS
// halving-tree rounding order exactly (commutative per-step operands).
__device__ inline float wsum(float p) {
  #pragma unroll
  for (int off = 32; off; off >>= 1) p += __shfl_xor(p, off, 64);
  return p;
}
__device__ inline float wmaxf(float p) {
  #pragma unroll
  for (int off = 32; off; off >>= 1) p = fmaxf(p, __shfl_xor(p, off, 64));
  return p;
}
__device__ inline void pick(float& v, int& i, float v2, int i2) {
  if (v2 > v || (v2 == v && i2 < i)) { v = v2; i = i2; }
}

// ---- radix-select: top-CDIM_ of 512 keys (8/lane, elem c = lane + 64k).
// Returns threshold t and rem = how many key==t elements to take (lowest idx).
__device__ inline void radix_topk(const unsigned* key, unsigned* s_hist,
                                  int l, unsigned& t_out, int& rem_out) {
  unsigned prefix = 0u;
  int rem = CDIM_;
  #pragma unroll
  for (int shift = 24; shift >= 0; shift -= 8) {
    unsigned hi_mask = (shift == 24) ? 0u : (0xffffffffu << (shift + 8));
    // clear
    #pragma unroll
    for (int i = 0; i < 4; ++i) s_hist[4 * l + i] = 0u;
    __threadfence_block();
    // fill
    #pragma unroll
    for (int k = 0; k < 8; ++k) {
      if ((key[k] & hi_mask) == (prefix & hi_mask))
        atomicAdd(&s_hist[(key[k] >> shift) & 255u], 1u);
    }
    __threadfence_block();
    unsigned h0 = s_hist[4 * l], h1 = s_hist[4 * l + 1];
    unsigned h2 = s_hist[4 * l + 2], h3 = s_hist[4 * l + 3];
    unsigned sum4 = h0 + h1 + h2 + h3;
    // inclusive suffix over lanes
    unsigned s = sum4;
    #pragma unroll
    for (int off = 1; off < 64; off <<= 1) {
      unsigned o = __shfl(s, min(l + off, 63), 64);
      s += (l + off < 64) ? o : 0u;
    }
    unsigned exclHigh = s - sum4;
    unsigned suf3 = exclHigh;
    unsigned suf2 = suf3 + h3;
    unsigned suf1 = suf2 + h2;
    unsigned suf0 = suf1 + h1;
    unsigned r = (unsigned)rem;
    unsigned enc = 0xffffffffu;
    if (suf0 < r && suf0 + h0 >= r) enc = (suf0 << 8) | (unsigned)(4 * l + 0);
    if (suf1 < r && suf1 + h1 >= r) enc = (suf1 << 8) | (unsigned)(4 * l + 1);
    if (suf2 < r && suf2 + h2 >= r) enc = (suf2 << 8) | (unsigned)(4 * l + 2);
    if (suf3 < r && suf3 + h3 >= r) enc = (suf3 << 8) | (unsigned)(4 * l + 3);
    #pragma unroll
    for (int off = 32; off; off >>= 1) {
      unsigned o = (unsigned)__shfl_xor((int)enc, off, 64);
      enc = (o < enc) ? o : enc;
    }
    rem -= (int)(enc >> 8);
    prefix |= (enc & 255u) << shift;
  }
  t_out = prefix;
  rem_out = rem;
}

// exact lax.top_k tie semantics: all key>t, plus first `rem` (by index) key==t
__device__ inline void build_mask(const unsigned* key, unsigned t, int rem,
                                  int l, unsigned long long lmask_lt,
                                  unsigned long long* m) {
  int eqbefore = 0;
  #pragma unroll
  for (int k = 0; k < 8; ++k) {
    bool gt = key[k] > t;
    bool eq = key[k] == t;
    unsigned long long beq = __ballot(eq);
    int rank = eqbefore + __popcll(beq & lmask_lt);
    bool sel = gt || (eq && rank < rem);
    m[k] = __ballot(sel);
    eqbefore += __popcll(beq);
  }
}

__global__ __launch_bounds__(256) void k_main(
    const float* __restrict__ gx, const float* __restrict__ gy,
    const float* __restrict__ enc_w, const float* __restrict__ enc_b,
    const float* __restrict__ dec_w, const float* __restrict__ dec_b,
    WsHeader* __restrict__ hdr)
{
  const int wid = threadIdx.x >> 6;
  const int l   = threadIdx.x & 63;
  const int row = blockIdx.x * 4 + wid;

  __shared__ float sh_xpad[4][XPAD_];
  __shared__ float sh_y[4][ODIM_];
  __shared__ float sh_yatt[4][ODIM_];
  __shared__ float sh_scr[4][HDIM_];   // h layout staging; aliased hist/pack

  float* s_xpad = sh_xpad[wid];
  float* s_y    = sh_y[wid];
  float* s_yatt = sh_yatt[wid];
  float* s_h    = sh_scr[wid];
  unsigned* s_hist = (unsigned*)sh_scr[wid];                       // 1 KB
  unsigned long long* s_pack = (unsigned long long*)&sh_scr[wid][256]; // 1 KB

  const unsigned long long lmask_lt = (l == 0) ? 0ull : ((1ull << l) - 1ull);

  const float* gxr = gx + row * IDIM_;
  const float* gyr = gy + row * ODIM_;

  #pragma unroll
  for (int t = l; t < XPAD_; t += 64)
    s_xpad[t] = (t >= 127 && t < 127 + IDIM_) ? gxr[t - 127] : 0.f;

  float x0 = gxr[l], x1 = gxr[l + 64];
  float y0 = gyr[l], y1 = gyr[l + 64];
  s_y[l] = y0; s_y[l + 64] = y1;
  const bool sq0 = (y0 == 0.f), sq1 = (y1 == 0.f);
  const bool sm_row = (__ballot((!sq0) || (!sq1)) == 0ull);

  const float denom_ll = (float)max(hdr->cnt_y_nz, 1u);
  const float denomh   = (float)max(hdr->cnt_rows_nm * (unsigned)HDIM_, 1u);

  int mprev[8];
  #pragma unroll
  for (int k = 0; k < 8; ++k) mprev[k] = 0;

  __threadfence_block();

  for (int iter = 0; iter < N_ITER_; ++iter) {
    // ---- ||y_res||  (replicates old 256-tree: pre-pair (l, l+64), butterfly)
    const float normy = sqrtf(wsum(y0 * y0 + y1 * y1));

    // ---- sim over 255 shifts; lane handles s = l + 64k
    float dot0 = 0, dot1 = 0, dot2 = 0, dot3 = 0;
    float nx0 = 0, nx1 = 0, nx2 = 0, nx3 = 0;
    #pragma unroll 4
    for (int j = 0; j < 128; ++j) {
      float yv = s_y[j];
      float a = s_xpad[l + j];
      float b = s_xpad[l + 64 + j];
      float c = s_xpad[l + 128 + j];
      float d = s_xpad[l + 192 + j];
      dot0 += a * yv; nx0 += a * a;
      dot1 += b * yv; nx1 += b * b;
      dot2 += c * yv; nx2 += c * c;
      dot3 += d * yv; nx3 += d * d;
    }
    float den0 = normy * sqrtf(nx0);
    float den1 = normy * sqrtf(nx1);
    float den2 = normy * sqrtf(nx2);
    float den3 = normy * sqrtf(nx3);
    float s0 = (den0 == 0.f) ? 0.f : dot0 / den0;
    float s1 = (den1 == 0.f) ? 0.f : dot1 / den1;
    float s2 = (den2 == 0.f) ? 0.f : dot2 / den2;
    float s3 = (den3 == 0.f) ? 0.f : dot3 / den3;
    if (l + 192 >= 255) s3 = -INFINITY;   // shift 255 doesn't exist

    // ---- argmax, first-occurrence semantics, replicating old tree order
    float cv = s0; int ci = l;
    pick(cv, ci, s2, l + 128);
    float cv2 = s1; int ci2 = l + 64;
    pick(cv2, ci2, s3, l + 192);
    pick(cv, ci, cv2, ci2);
    #pragma unroll
    for (int off = 32; off; off >>= 1) {
      float ov = __shfl_xor(cv, off, 64);
      int   oi = __shfl_xor(ci, off, 64);
      pick(cv, ci, ov, oi);
    }
    const int theta = ci;

    // ---- y_al = x_aug[theta]  (zero-padded window == s_xpad[theta + j])
    float yal0 = s_xpad[theta + l];
    float yal1 = s_xpad[theta + l + 64];

    // ---- softmax(y_al * y_res / T) -> y_att
    float z0 = yal0 * y0 / TEMPER_;
    float z1 = yal1 * y1 / TEMPER_;
    float zmax = wmaxf(fmaxf(z0, z1));
    float e0 = expf(z0 - zmax), e1 = expf(z1 - zmax);
    float esum = wsum(e0 + e1);
    float ya0 = yal0 * (e0 / esum);
    float ya1 = yal1 * (e1 / esum);
    s_yatt[l] = ya0;
    s_yatt[l + 64] = ya1;
    __threadfence_block();

    // ---- h = y_att @ enc_w + enc_b   (float4 coalesced; c = 4l+{0..3}, +256)
    const float* wA = enc_w + 4 * l;
    const float* wB = enc_w + 256 + 4 * l;
    float a0 = 0, a1 = 0, a2 = 0, a3 = 0, b0 = 0, b1 = 0, b2 = 0, b3 = 0;
    for (int i4 = 0; i4 < 32; ++i4) {
      float4 ya4 = *(const float4*)&s_yatt[4 * i4];
      #pragma unroll
      for (int u = 0; u < 4; ++u) {
        float ya = (u == 0) ? ya4.x : (u == 1) ? ya4.y : (u == 2) ? ya4.z : ya4.w;
        int i = 4 * i4 + u;
        float4 w4a = *(const float4*)(wA + i * HDIM_);
        float4 w4b = *(const float4*)(wB + i * HDIM_);
        a0 += ya * w4a.x; a1 += ya * w4a.y; a2 += ya * w4a.z; a3 += ya * w4a.w;
        b0 += ya * w4b.x; b1 += ya * w4b.y; b2 += ya * w4b.z; b3 += ya * w4b.w;
      }
    }
    {
      float4 ebA = *(const float4*)(enc_b + 4 * l);
      float4 ebB = *(const float4*)(enc_b + 256 + 4 * l);
      float4 hA = {a0 + ebA.x, a1 + ebA.y, a2 + ebA.z, a3 + ebA.w};
      float4 hB = {b0 + ebB.x, b1 + ebB.y, b2 + ebB.z, b3 + ebB.w};
      *(float4*)&s_h[4 * l] = hA;
      *(float4*)&s_h[256 + 4 * l] = hB;
    }
    __threadfence_block();
    float h[8];
    #pragma unroll
    for (int k = 0; k < 8; ++k) h[k] = s_h[l + 64 * k];

    // ---- hsr
    unsigned key[8];
    #pragma unroll
    for (int k = 0; k < 8; ++k) key[k] = __float_as_uint(h[k] * h[k]);

    float row_lh = 0.f;
    unsigned long long mcur[8];
    if (iter == 0) {
      unsigned t; int rem;
      radix_topk(key, s_hist, l, t, rem);
      build_mask(key, t, rem, l, lmask_lt, mcur);
      #pragma unroll
      for (int k = 0; k < 8; ++k) mprev[k] += (int)((mcur[k] >> l) & 1ull);
    } else {
      unsigned t0; int rem0;
      radix_topk(key, s_hist, l, t0, rem0);
      unsigned long long m0[8];
      build_mask(key, t0, rem0, l, lmask_lt, m0);
      float lacc = 0.f;
      #pragma unroll
      for (int k = 0; k < 8; ++k) {
        if (((m0[k] >> l) & 1ull) && mprev[k] > 0 && !sm_row) {
          float mi = (float)mprev[k];          // mask_prev * mask_cur0
          float d = h[k] - (1.f - mi);
          lacc += (d * d) / denomh;
        }
      }
      row_lh = wsum(lacc);
      // zero previously-selected, re-select
      unsigned kz[8];
      #pragma unroll
      for (int k = 0; k < 8; ++k) {
        if (mprev[k] > 0) h[k] = 0.f;
        kz[k] = __float_as_uint(h[k] * h[k]);
      }
      unsigned t; int rem;
      radix_topk(kz, s_hist, l, t, rem);
      build_mask(kz, t, rem, l, lmask_lt, mcur);
      #pragma unroll
      for (int k = 0; k < 8; ++k) mprev[k] += (int)((mcur[k] >> l) & 1ull);
    }
    // keep only current top-k; compact (c ascending) into s_pack
    int scount = 0;
    #pragma unroll
    for (int k = 0; k < 8; ++k) {
      unsigned long long mk = mcur[k];
      if ((mk >> l) & 1ull) {
        int pos = scount + __popcll(mk & lmask_lt);
        s_pack[pos] = (((unsigned long long)__float_as_uint(h[k])) << 32)
                      | (unsigned long long)(unsigned)(l + 64 * k);
      }
      scount += (int)__popcll(mk);
    }
    __threadfence_block();

    // ---- y_ele = h @ dec_w + dec_b  (only 128 selected channels, c ascending)
    float acc0 = 0.f, acc1 = 0.f;
    #pragma unroll 8
    for (int j = 0; j < CDIM_; ++j) {
      unsigned long long pk = s_pack[j];
      float hv = __uint_as_float((unsigned)(pk >> 32));
      const float* wr = dec_w + (unsigned)(pk & 0xffffffffull) * (unsigned)ODIM_;
      acc0 += hv * wr[l];
      acc1 += hv * wr[l + 64];
    }
    float ye0 = acc0 + dec_b[l];
    float ye1 = acc1 + dec_b[l + 64];

    // ---- energy_loss
    float tshift  = fabsf((float)theta - 127.f);
    float menergy = tshift + 1.f;
    bool  mmask   = (tshift > ENERGY_TH_);
    float d0 = ye0 - y0, d1 = ye1 - y1;
    float ll0 = sq0 ? 0.f : d0 * d0; ll0 = ll0 / denom_ll; ll0 = mmask ? 0.f : ll0; ll0 = ll0 / menergy;
    float ll1 = sq1 ? 0.f : d1 * d1; ll1 = ll1 / denom_ll; ll1 = mmask ? 0.f : ll1; ll1 = ll1 / menergy;
    float row_ll = wsum(ll0 + ll1);
    if (l == 0) atomicAdd(&hdr->loss[iter], (double)(row_ll + row_lh));

    // ---- residual updates
    int src0 = l + 127 - theta;
    int src1 = l + 64 + 127 - theta;
    float xe0 = (src0 >= 0 && src0 < ODIM_) ? s_yatt[src0] : 0.f;
    float xe1 = (src1 >= 0 && src1 < ODIM_) ? s_yatt[src1] : 0.f;
    y0 -= ye0; y1 -= ye1;
    x0 -= xe0; x1 -= xe1;
    s_y[l] = y0; s_y[l + 64] = y1;
    s_xpad[127 + l] = x0; s_xpad[127 + 64 + l] = x1;
    __threadfence_block();
  }
}

__global__ void k_finish(const WsHeader* __restrict__ h, float* __restrict__ out) {
  double s = (h->loss[0] + h->loss[1] + h->loss[2] + h->loss[3]) * 0.25;
  out[0] = (float)s;
}

extern "C" void kernel_launch(void* const* d_in, const int* in_sizes, int n_in,
                              void* d_out, int out_size, void* d_ws, size_t ws_size,
                              hipStream_t stream) {
  (void)in_sizes; (void)n_in; (void)out_size; (void)ws_size;
  const float* x     = (const float*)d_in[0];
  const float* y     = (const float*)d_in[1];
  const float* enc_w = (const float*)d_in[2];
  const float* enc_b = (const float*)d_in[3];
  const float* dec_w = (const float*)d_in[4];
  const float* dec_b = (const float*)d_in[5];
  float* out = (float*)d_out;
  WsHeader* hdr = (WsHeader*)d_ws;

  hipLaunchKernelGGL(k_zero,   dim3(1),          dim3(1),   0, stream, hdr);
  hipLaunchKernelGGL(k_count,  dim3(NROWS_),     dim3(128), 0, stream, y, hdr);
  hipLaunchKernelGGL(k_main,   dim3(NROWS_ / 4), dim3(256), 0, stream,
                     x, y, enc_w, enc_b, dec_w, dec_b, hdr);
  hipLaunchKernelGGL(k_finish, dim3(1),          dim3(1),   0, stream, hdr, out);
}